// Round 9
// baseline (128.923 us; speedup 1.0000x reference)
//
#include <hip/hip_runtime.h>
#include <hip/hip_bf16.h>

// Problem constants
#define NB   16
#define CIN  256
#define COUT 256
#define HH   32
#define WW   32
#define HW   1024           // 32*32
#define KK   9
#define CK   2304           // CIN*KK  (ordered k*256 + c, tap-major)

typedef __bf16 bf16x8 __attribute__((ext_vector_type(8)));
typedef float  f32x4  __attribute__((ext_vector_type(4)));

__device__ __forceinline__ unsigned short f2bf(float f) {
    unsigned int u = __float_as_uint(f);
    u += 0x7FFFu + ((u >> 16) & 1u);          // round-nearest-even
    return (unsigned short)(u >> 16);
}
__device__ __forceinline__ float bfhi(unsigned int u) {   // high bf16 -> f32
    return __uint_as_float(u & 0xFFFF0000u);
}
__device__ __forceinline__ float bflo(unsigned int u) {   // low bf16 -> f32
    return __uint_as_float(u << 16);
}

// ---------------------------------------------------------------- wconv ----
// weight fp32 [O][C][3][3] -> bf16 [O][k*256+c]  (tap-major)
__global__ __launch_bounds__(256) void wconv_kernel(const float* __restrict__ w,
                                                    unsigned short* __restrict__ wbf) {
    __shared__ float ls[CK];
    const int o = blockIdx.x;
    const float* wo = w + (size_t)o * CK;
#pragma unroll
    for (int i = threadIdx.x; i < CK; i += 256) ls[i] = wo[i];
    __syncthreads();
    unsigned short* dst = wbf + (size_t)o * CK;
#pragma unroll
    for (int i = threadIdx.x; i < CK; i += 256) {
        int k = i >> 8, c = i & 255;
        dst[i] = f2bf(ls[c * KK + k]);        // bank stride 9: conflict-free
    }
}

// ------------------------------------------------------------------- xt ----
// x fp32 [n][c][hw] -> xtb bf16 [n][hw][c]   (64x64 LDS tile transpose)
__global__ __launch_bounds__(256) void xt_kernel(const float* __restrict__ x,
                                                 unsigned short* __restrict__ xtb) {
    __shared__ float ls[64][65];
    const int c0  = blockIdx.x * 64;
    const int hw0 = blockIdx.y * 64;
    const int n   = blockIdx.z;
    const int t   = threadIdx.x;
    {
        int c = t >> 2, q = t & 3;
        const float4* base = (const float4*)(x + ((size_t)(n * CIN + c0 + c)) * HW + hw0 + q * 16);
#pragma unroll
        for (int j = 0; j < 4; ++j) {
            float4 v = base[j];
            ls[c][q * 16 + j * 4 + 0] = v.x;
            ls[c][q * 16 + j * 4 + 1] = v.y;
            ls[c][q * 16 + j * 4 + 2] = v.z;
            ls[c][q * 16 + j * 4 + 3] = v.w;
        }
    }
    __syncthreads();
    {
        int hw = t >> 2, seg = (t & 3) * 16;
        unsigned int dw[8];
#pragma unroll
        for (int j = 0; j < 8; ++j) {
            float f0 = ls[seg + 2 * j][hw];
            float f1 = ls[seg + 2 * j + 1][hw];
            dw[j] = (unsigned)f2bf(f0) | ((unsigned)f2bf(f1) << 16);
        }
        uint4* dst = (uint4*)(xtb + ((size_t)(n * HW + hw0 + hw)) * CIN + c0 + seg);
        dst[0] = *(uint4*)&dw[0];
        dst[1] = *(uint4*)&dw[4];
    }
}

// ---------------------------------------------------------------- fused ----
// Per block: out[0..255][hw0..hw0+63] for one image. BM=256, BN=64.
// 512 threads / 8 waves, wave tile 32(o) x 64(hw).
// ONE BARRIER PER TAP (BK=256): Bs[2] = two 64hw x 256ck bf16 buffers
// (64 KB). Per tap: load A-frags (global->VGPR, consumed by the first
// MFMAs), 2 MFMA subs, mid-tap issue next-tap offsets+corner loads
// (~1300 cyc of MFMA cover), 2 more MFMA subs, then 4 lerp+ds_write
// builds into the other buffer, one __syncthreads. All global loads are
// issued AND consumed within the tap, so the compiler's vmcnt(0) drain
// at the barrier is nearly free — 9 exposure events instead of 36.
// XCD-aware decode keeps each image's xtb slice + wbf in one XCD L2.
__global__ __launch_bounds__(512, 2) void fused_kernel(const unsigned short* __restrict__ wbf,
                                                       const unsigned short* __restrict__ xtb,
                                                       const float* __restrict__ off,
                                                       float* __restrict__ out) {
    __shared__ unsigned short Bs[2][64 * 256];   // 64 KB

    const int tid  = threadIdx.x;
    const int wv   = tid >> 6;                // 0..7  (M position, 32 rows each)
    const int lane = tid & 63;
    const int quad = lane >> 4;
    const int l15  = lane & 15;

    const int hwl = tid >> 3;                 // 0..63  (B row this thread builds)
    const int seg = tid & 7;                  // 8-channel segment within 64

    // XCD-aware decode (consecutive ids round-robin XCDs)
    const int id  = blockIdx.x;
    const int n   = ((id & 7) << 1) | ((id >> 3) & 1);
    const int hw0 = (id >> 4) * 64;

    const int hw = hw0 + hwl;
    const int h  = hw >> 5, w = hw & 31;

    const uint4*  xb4  = (const uint4*)(xtb + (size_t)n * HW * CIN);
    const float2* offp = (const float2*)(off + ((size_t)n * HW + hw) * (2 * KK));
    const unsigned short* Abase = wbf + (size_t)(wv * 32 + l15) * CK + quad * 8;

    f32x4 acc[2][4] = {};

    auto setup = [&](float2 o, int tap, float wg[4], int ix[4]) {
        float py = (float)(h + tap / 3 - 1) + o.x;
        float px = (float)(w + tap % 3 - 1) + o.y;
        float y0f = floorf(py), x0f = floorf(px);
        float ly = py - y0f, lx = px - x0f;
        int y0 = (int)y0f, x0 = (int)x0f;
#pragma unroll
        for (int c2 = 0; c2 < 4; ++c2) {
            int yy = y0 + (c2 >> 1);
            int xx = x0 + (c2 & 1);
            float wy = (c2 >> 1) ? ly : 1.0f - ly;
            float wx = (c2 & 1) ? lx : 1.0f - lx;
            bool v = (yy >= 0) && (yy < HH) && (xx >= 0) && (xx < WW);
            wg[c2] = v ? wy * wx : 0.0f;
            int yc = yy < 0 ? 0 : (yy > HH - 1 ? HH - 1 : yy);
            int xc = xx < 0 ? 0 : (xx > WW - 1 ? WW - 1 : xx);
            ix[c2] = yc * WW + xc;
        }
    };

    // issue all 16 corner loads for a tap (4 subs x 4 corners)
    auto loadc = [&](uint4 cr[16], const int ix[4]) {
#pragma unroll
        for (int s = 0; s < 4; ++s)
#pragma unroll
            for (int c2 = 0; c2 < 4; ++c2)
                cr[s * 4 + c2] = xb4[(size_t)ix[c2] * 32 + s * 8 + seg];
    };

    // lerp sub-chunk s -> swizzled ds_write_b128 into Bs[nb]
    auto buildB = [&](int nb, int s, const uint4* cr, const float wg[4]) {
        unsigned u0[4], u1[4], u2[4], u3[4];
        *(uint4*)u0 = cr[0]; *(uint4*)u1 = cr[1];
        *(uint4*)u2 = cr[2]; *(uint4*)u3 = cr[3];
        unsigned dw[4];
#pragma unroll
        for (int d = 0; d < 4; ++d) {
            float2 lv;
            lv.x = wg[0] * bflo(u0[d]) + wg[1] * bflo(u1[d])
                 + wg[2] * bflo(u2[d]) + wg[3] * bflo(u3[d]);
            lv.y = wg[0] * bfhi(u0[d]) + wg[1] * bfhi(u1[d])
                 + wg[2] * bfhi(u2[d]) + wg[3] * bfhi(u3[d]);
            __hip_bfloat162 bb = __float22bfloat162_rn(lv);
            dw[d] = *(unsigned*)&bb;
        }
        *(uint4*)&Bs[nb][hwl * 256 + (s * 8 + (seg ^ (hwl & 7))) * 8] = *(uint4*)dw;
    };

    // MFMA for one 64-ck sub-chunk from Bs[pb]
    auto mfma_sub = [&](int pb, int s, const bf16x8 af2[2][2]) {
        bf16x8 bfr[4][2];
#pragma unroll
        for (int ni = 0; ni < 4; ++ni)
#pragma unroll
            for (int hh = 0; hh < 2; ++hh) {
                int row = ni * 16 + l15;
                int ch  = s * 8 + ((hh * 4 + quad) ^ (row & 7));
                bfr[ni][hh] = *(const bf16x8*)&Bs[pb][row * 256 + ch * 8];
            }
#pragma unroll
        for (int mi = 0; mi < 2; ++mi)
#pragma unroll
            for (int ni = 0; ni < 4; ++ni) {
                acc[mi][ni] = __builtin_amdgcn_mfma_f32_16x16x32_bf16(af2[mi][0], bfr[ni][0], acc[mi][ni], 0, 0, 0);
                acc[mi][ni] = __builtin_amdgcn_mfma_f32_16x16x32_bf16(af2[mi][1], bfr[ni][1], acc[mi][ni], 0, 0, 0);
            }
    };

    // ---- prologue: build B(0) into Bs[0]
    {
        float wg0[4]; int ix0[4]; uint4 cr0[16];
        float2 o0 = offp[0];
        setup(o0, 0, wg0, ix0);
        loadc(cr0, ix0);
#pragma unroll
        for (int s = 0; s < 4; ++s) buildB(0, s, &cr0[s * 4], wg0);
    }
    __syncthreads();

    // ---- 9 taps, one barrier each
    for (int tap = 0; tap < 9; ++tap) {
        const int pb = tap & 1;

        // A fragments for this tap (16 x b128; first use = first MFMA below)
        bf16x8 af[4][2][2];
        {
            const unsigned short* pA = Abase + tap * 256;
#pragma unroll
            for (int s = 0; s < 4; ++s)
#pragma unroll
                for (int mi = 0; mi < 2; ++mi)
#pragma unroll
                    for (int hh = 0; hh < 2; ++hh)
                        af[s][mi][hh] = *(const bf16x8*)(pA + (size_t)mi * 16 * CK + s * 64 + hh * 32);
        }

        // next-tap offset load issued early (consumed mid-tap)
        float2 onxt;
        if (tap < 8) onxt = offp[tap + 1];

        mfma_sub(pb, 0, af[0]);
        mfma_sub(pb, 1, af[1]);

        // mid-tap: setup + corner loads for tap+1 (consumed after sub 3)
        float wgn[4]; int ixn[4]; uint4 crs[16];
        if (tap < 8) {
            setup(onxt, tap + 1, wgn, ixn);
            loadc(crs, ixn);
        }

        mfma_sub(pb, 2, af[2]);
        mfma_sub(pb, 3, af[3]);

        if (tap < 8) {
#pragma unroll
            for (int s = 0; s < 4; ++s) buildB(pb ^ 1, s, &crs[s * 4], wgn);
        }
        __syncthreads();
    }

    // ---- epilogue: D layout col = lane&15, row = quad*4 + reg
    float* opnt = out + (size_t)n * COUT * HW + hw0;
#pragma unroll
    for (int mi = 0; mi < 2; ++mi)
#pragma unroll
        for (int ni = 0; ni < 4; ++ni) {
            int col = ni * 16 + l15;
#pragma unroll
            for (int rr = 0; rr < 4; ++rr) {
                int row = wv * 32 + mi * 16 + quad * 4 + rr;
                opnt[(size_t)row * HW + col] = acc[mi][ni][rr];
            }
        }
}

// --------------------------------------------------------------- launch ----
extern "C" void kernel_launch(void* const* d_in, const int* in_sizes, int n_in,
                              void* d_out, int out_size, void* d_ws, size_t ws_size,
                              hipStream_t stream) {
    const float* x   = (const float*)d_in[0];   // [16][256][32][32]
    const float* off = (const float*)d_in[1];   // [16][1024][18]
    const float* wt  = (const float*)d_in[2];   // [256][256][3][3]
    float* out = (float*)d_out;                 // [16][256][32][32]

    unsigned short* wbf = (unsigned short*)d_ws;                        // 1179648 B
    unsigned short* xtb = (unsigned short*)((char*)d_ws + 1179648);     // 8388608 B

    wconv_kernel<<<256, 256, 0, stream>>>(wt, wbf);
    xt_kernel<<<dim3(4, 16, 16), 256, 0, stream>>>(x, xtb);
    fused_kernel<<<256, 512, 0, stream>>>(wbf, xtb, off, out);
}